// Round 4
// baseline (719.386 us; speedup 1.0000x reference)
//
#include <hip/hip_runtime.h>

#define NN 2048
#define HH 256
#define RR 22
#define EE 20000

typedef unsigned short u16;
typedef unsigned int   u32;
typedef __bf16 bf16x8 __attribute__((ext_vector_type(8)));
typedef float  f32x16 __attribute__((ext_vector_type(16)));
typedef u16    u16x8  __attribute__((ext_vector_type(8)));

__device__ __forceinline__ u16 f2bf(float f){
  union{float f; u32 u;} v; v.f = f; u32 u = v.u;
  return (u16)((u + 0x7FFFu + ((u>>16)&1u)) >> 16);
}
__device__ __forceinline__ float bf2f(u16 v){
  union{u32 u; float f;} x; x.u = ((u32)v) << 16; return x.f;
}

// ---- CSR build: full-device global-atomic version (round-1/3 proven) ------
// 22-block LDS version regressed +66us (8.6% of CUs). Keep device-wide.
__global__ void count_k(const int* __restrict__ ei, int* __restrict__ cnt){
  int idx = blockIdx.x*256 + threadIdx.x;
  if (idx >= RR*EE) return;
  int r = idx / EE, e = idx - r*EE;
  int dst = ei[(r*2+1)*EE + e];
  atomicAdd(&cnt[r*NN + dst], 1);
}

__global__ void scan_k(const int* __restrict__ cnt, int* __restrict__ offs,
                       int* __restrict__ cursor){
  int r = blockIdx.x, t = threadIdx.x;   // 22 blocks x 256 threads
  __shared__ int part[256];
  int base = r*NN;
  int loc[8]; int s = 0;
  #pragma unroll
  for (int u=0; u<8; u++){ loc[u] = cnt[base + t*8 + u]; s += loc[u]; }
  part[t] = s;
  __syncthreads();
  for (int off=1; off<256; off<<=1){
    int v = (t>=off) ? part[t-off] : 0;
    __syncthreads();
    part[t] += v;
    __syncthreads();
  }
  int run = r*EE + part[t] - s;
  #pragma unroll
  for (int u=0; u<8; u++){
    offs[base + t*8+u]   = run;
    cursor[base + t*8+u] = run;
    run += loc[u];
  }
}

__global__ void scatter_k(const int* __restrict__ ei, int* __restrict__ cursor,
                          int* __restrict__ csr){
  int idx = blockIdx.x*256 + threadIdx.x;
  if (idx >= RR*EE) return;
  int r = idx / EE, e = idx - r*EE;
  int src = ei[(r*2+0)*EE + e];
  int dst = ei[(r*2+1)*EE + e];
  int pos = atomicAdd(&cursor[r*NN + dst], 1);
  csr[pos] = src;
}

// ---- prep: weights for BOTH layers + x0->bf16 cast, one launch ------------
__global__ void prep_k(const float* __restrict__ Wl, const float* __restrict__ Wr,
                       const float* __restrict__ bl, const float* __restrict__ x0,
                       u16* __restrict__ Bt2, float* __restrict__ bias2,
                       u16* __restrict__ xb){
  int b = blockIdx.x;
  if (b < (2*23*65536)/256){
    int idx = b*256 + threadIdx.x;
    int l  = idx / (23*65536);
    int r2 = idx - l*(23*65536);
    int plane = r2 >> 16, rem = r2 & 65535;
    if (plane < RR){
      Bt2[idx] = f2bf(Wl[((size_t)l*RR + plane)*65536 + rem]);
    } else {
      float s = 0.f;
      for (int r=0;r<RR;r++) s += Wr[((size_t)l*RR + r)*65536 + rem];
      Bt2[idx] = f2bf(s);
    }
    if (plane == 0 && rem < HH){
      float bsum = 0.f;
      for (int r=0;r<RR;r++) bsum += bl[((size_t)l*RR + r)*HH + rem];
      bias2[l*HH + rem] = bsum;
    }
  } else {
    int idx = (b - (2*23*65536)/256)*256 + threadIdx.x;   // 65536 threads
    const float4* p = (const float4*)x0 + (size_t)idx*2;
    float4 a = p[0], c = p[1];
    u16x8 st;
    st[0]=f2bf(a.x); st[1]=f2bf(a.y); st[2]=f2bf(a.z); st[3]=f2bf(a.w);
    st[4]=f2bf(c.x); st[5]=f2bf(c.y); st[6]=f2bf(c.z); st[7]=f2bf(c.w);
    ((u16x8*)xb)[idx] = st;
  }
}

// ---- gather-mean into global bf16 G[p][n][h] ------------------------------
__global__ void __launch_bounds__(256) gather_k(
    const u16* __restrict__ xb, const int* __restrict__ offs,
    const int* __restrict__ cnt, const int* __restrict__ csr,
    u16* __restrict__ G)
{
  int p    = blockIdx.y;
  int m0   = blockIdx.x * 32;
  int wv   = threadIdx.x >> 6;
  int lane = threadIdx.x & 63;
  int half = lane >> 5;
  int c    = (lane & 31) * 8;

  for (int t = 0; t < 4; t++){
    int n   = m0 + wv*8 + t*2 + half;
    int off = offs[p*NN + n];
    int deg = cnt [p*NN + n];
    int dmax = max(deg, __shfl_xor(deg, 32));
    float a[8];
    #pragma unroll
    for (int u=0;u<8;u++) a[u] = 0.f;
    for (int e = 0; e < dmax; e++){
      if (e < deg){
        int s = csr[off + e];
        u16x8 v = *(const u16x8*)(xb + (size_t)s*HH + c);
        #pragma unroll
        for (int u=0;u<8;u++) a[u] += bf2f(v[u]);
      }
    }
    float inv = 1.0f / fmaxf((float)deg, 1.0f);
    u16x8 st;
    #pragma unroll
    for (int u=0;u<8;u++) st[u] = f2bf(a[u]*inv);
    *(u16x8*)(G + ((size_t)p*NN + n)*HH + c) = st;
  }
}

// ---- fused stacked-K GEMM + split-K LDS reduce + bias + relu + casts ------
__global__ void __launch_bounds__(512) fgr_k(
    const u16* __restrict__ G, const u16* __restrict__ xb,
    const u16* __restrict__ Bt, const float* __restrict__ bias,
    float* __restrict__ x1, u16* __restrict__ xbo)
{
  __shared__ float red[8][32][32];   // 32 KB
  int m0   = blockIdx.x * 32;
  int y    = blockIdx.y;
  int wid  = threadIdx.x >> 6;
  int lane = threadIdx.x & 63;
  int c    = wid & 1;
  int kc   = wid >> 1;
  int col  = y*64 + c*32 + (lane & 31);
  int khalf = (lane >> 5) * 8;
  int arow  = lane & 31;

  f32x16 acc;
  #pragma unroll
  for (int i=0;i<16;i++) acc[i]=0.f;

  int p0 = kc*6, p1 = min(p0+6, 23);
  for (int p = p0; p < p1; p++){
    const u16* Ap = ((p < RR) ? (G + (size_t)p*NN*HH) : xb)
                    + (size_t)(m0 + arow)*HH + khalf;
    const u16* Bp = Bt + (size_t)p*65536 + (size_t)col*HH + khalf;
    #pragma unroll
    for (int kk = 0; kk < HH; kk += 16){
      bf16x8 af = *(const bf16x8*)(Ap + kk);
      bf16x8 bf = *(const bf16x8*)(Bp + kk);
      acc = __builtin_amdgcn_mfma_f32_32x32x16_bf16(af, bf, acc, 0, 0, 0);
    }
  }
  #pragma unroll
  for (int reg=0; reg<16; reg++){
    int row = (reg&3) + 8*(reg>>2) + 4*(lane>>5);
    red[wid][row][lane & 31] = acc[reg];
  }
  __syncthreads();

  int t    = threadIdx.x;
  int cc   = t >> 8;
  int rrow = (t >> 3) & 31;
  int c4   = (t & 7) * 4;
  float4 v = *(const float4*)&red[cc][rrow][c4];
  #pragma unroll
  for (int k=1;k<4;k++){
    float4 w = *(const float4*)&red[k*2+cc][rrow][c4];
    v.x+=w.x; v.y+=w.y; v.z+=w.z; v.w+=w.w;
  }
  int gcol = y*64 + cc*32 + c4;
  float4 b = *(const float4*)(bias + gcol);
  v.x = fmaxf(v.x+b.x, 0.f);
  v.y = fmaxf(v.y+b.y, 0.f);
  v.z = fmaxf(v.z+b.z, 0.f);
  v.w = fmaxf(v.w+b.w, 0.f);
  size_t o = (size_t)(m0 + rrow)*HH + gcol;
  *(float4*)(x1 + o) = v;
  ushort4 st; st.x=f2bf(v.x); st.y=f2bf(v.y); st.z=f2bf(v.z); st.w=f2bf(v.w);
  *(ushort4*)(xbo + o) = st;
}

// ---- coefficients: m[n][r], p[n][r] = m*a ---------------------------------
__global__ void coeff_k(const float* __restrict__ x2, const float* __restrict__ Wa,
                        const float* __restrict__ ba, const float* __restrict__ Wm,
                        const float* __restrict__ bm,
                        float* __restrict__ mbuf, float* __restrict__ pbuf){
  int idx = blockIdx.x*256 + threadIdx.x;   // NN*RR = 45056 exact
  int n = idx / RR, r = idx - n*RR;
  const float4* xr = (const float4*)(x2 + (size_t)n*HH);
  const float4* wa = (const float4*)(Wa + (size_t)r*HH);
  const float4* wm = (const float4*)(Wm + (size_t)r*HH);
  float da=0.f, dm=0.f;
  #pragma unroll 4
  for (int h=0; h<HH/4; h++){
    float4 xv = xr[h], av = wa[h], mv = wm[h];
    da += xv.x*av.x + xv.y*av.y + xv.z*av.z + xv.w*av.w;
    dm += xv.x*mv.x + xv.y*mv.y + xv.z*mv.z + xv.w*mv.w;
  }
  float a = fmaxf(da + ba[r], 0.f);
  float m = fmaxf(dm + bm[r], 0.f);
  mbuf[idx] = m;
  pbuf[idx] = m*a;
}

// ---- final: out[i,j] = sum_r m[i,r]*adj[i,j,r] + sum_r m[i,r]*a[i,r] ------
// Round-4 rewrite: stage the block's contiguous 22.5 KB adj slice into LDS
// with coalesced float4 loads (22 wave-instrs x 16 lines vs 704 scattered
// L1 line-requests/wave before), then dot rows out of LDS. stride-22 LDS
// read = 4-way bank conflict (mild; LDS far from ceiling).
__global__ void __launch_bounds__(256) final_k(
    const float* __restrict__ adj, const float* __restrict__ mbuf,
    const float* __restrict__ pbuf, float* __restrict__ out){
  __shared__ float sadj[256*RR];                 // 22528 B
  int i  = blockIdx.y;
  int jb = blockIdx.x*256;
  int t  = threadIdx.x;
  const float4* base = (const float4*)(adj + ((size_t)i*NN + jb)*RR);  // 16B-aligned: (i*NN+jb) even
  #pragma unroll
  for (int k = 0; k < 6; k++){
    int idx = k*256 + t;
    if (idx < (256*RR)/4) ((float4*)sadj)[idx] = base[idx];
  }
  float mv[RR];
  float s = 0.f;
  #pragma unroll
  for (int r=0;r<RR;r++){ mv[r] = mbuf[i*RR+r]; s += pbuf[i*RR+r]; }
  __syncthreads();
  float acc = s;
  const float* row = &sadj[t*RR];
  #pragma unroll
  for (int r=0;r<RR;r++) acc += mv[r]*row[r];
  out[(size_t)i*NN + jb + t] = acc;
}

extern "C" void kernel_launch(void* const* d_in, const int* in_sizes, int n_in,
                              void* d_out, int out_size, void* d_ws, size_t ws_size,
                              hipStream_t stream) {
  const float* x0  = (const float*)d_in[0];
  const float* adj = (const float*)d_in[1];
  const float* Wl  = (const float*)d_in[2];
  const float* bl  = (const float*)d_in[3];
  const float* Wr  = (const float*)d_in[4];
  const float* Wa  = (const float*)d_in[5];
  const float* ba  = (const float*)d_in[6];
  const float* Wm  = (const float*)d_in[7];
  const float* bm  = (const float*)d_in[8];
  const int*   ei  = (const int*)d_in[9];
  float* out = (float*)d_out;

  char* w = (char*)d_ws;
  auto alloc = [&](size_t bytes){ char* p = w; w += (bytes + 255) & ~255ull; return p; };
  int*   cnt    = (int*)  alloc((size_t)RR*NN*4);
  int*   offs   = (int*)  alloc((size_t)RR*NN*4);
  int*   cursor = (int*)  alloc((size_t)RR*NN*4);
  int*   csr    = (int*)  alloc((size_t)RR*EE*4);
  u16*   Bt2    = (u16*)  alloc((size_t)2*(RR+1)*HH*HH*2);
  float* bias2  = (float*)alloc((size_t)2*HH*4);
  u16*   G      = (u16*)  alloc((size_t)RR*NN*HH*2);   // 22 MB stacked-K bf16
  u16*   xb0    = (u16*)  alloc((size_t)NN*HH*2);
  u16*   xb1    = (u16*)  alloc((size_t)NN*HH*2);
  float* x1     = (float*)alloc((size_t)NN*HH*4);
  float* mbuf   = (float*)alloc((size_t)NN*RR*4);
  float* pbuf   = (float*)alloc((size_t)NN*RR*4);

  hipMemsetAsync(cnt, 0, (size_t)RR*NN*4, stream);
  count_k  <<<(RR*EE+255)/256, 256, 0, stream>>>(ei, cnt);
  scan_k   <<<RR, 256, 0, stream>>>(cnt, offs, cursor);
  scatter_k<<<(RR*EE+255)/256, 256, 0, stream>>>(ei, cursor, csr);
  prep_k<<<(2*23*65536)/256 + (NN*HH/8)/256, 256, 0, stream>>>(Wl, Wr, bl, x0,
                                                               Bt2, bias2, xb0);
  // layer 0
  gather_k<<<dim3(NN/32, RR), 256, 0, stream>>>(xb0, offs, cnt, csr, G);
  fgr_k   <<<dim3(NN/32, 4), 512, 0, stream>>>(G, xb0, Bt2, bias2, x1, xb1);
  // layer 1
  gather_k<<<dim3(NN/32, RR), 256, 0, stream>>>(xb1, offs, cnt, csr, G);
  fgr_k   <<<dim3(NN/32, 4), 512, 0, stream>>>(G, xb1, Bt2 + (size_t)(RR+1)*HH*HH,
                                               bias2 + HH, x1, xb0);

  coeff_k<<<(NN*RR)/256, 256, 0, stream>>>(x1, Wa, ba, Wm, bm, mbuf, pbuf);
  final_k<<<dim3(NN/256, NN), 256, 0, stream>>>(adj, mbuf, pbuf, out);
}

// Round 5
// 697.932 us; speedup vs baseline: 1.0307x; 1.0307x over previous
//
#include <hip/hip_runtime.h>

#define NN 2048
#define HH 256
#define RR 22
#define EE 20000
#define CH 16          /* chunks per relation for atomic-free CSR build */
#define EPC (EE/CH)    /* 1250 edges per chunk */

typedef unsigned short u16;
typedef unsigned int   u32;
typedef __bf16 bf16x8 __attribute__((ext_vector_type(8)));
typedef float  f32x16 __attribute__((ext_vector_type(16)));
typedef u16    u16x8  __attribute__((ext_vector_type(8)));

__device__ __forceinline__ u16 f2bf(float f){
  union{float f; u32 u;} v; v.f = f; u32 u = v.u;
  return (u16)((u + 0x7FFFu + ((u>>16)&1u)) >> 16);
}
__device__ __forceinline__ float bf2f(u16 v){
  union{u32 u; float f;} x; x.u = ((u32)v) << 16; return x.f;
}

// ---- CSR build v2: ZERO device atomics, full device parallelism -----------
// Round-2 lesson: 22-block LDS version starved CUs (+66us). Round 3/4 used
// 880K contended device atomicAdds (theory: 30-80us at the coherence point).
// v2: 352 blocks (22 rel x 16 chunks); all atomics stay in LDS.

// per-chunk LDS histogram -> H[r][c][dst], coalesced, no global atomics
__global__ void __launch_bounds__(256) hist_k(const int* __restrict__ ei,
                                              int* __restrict__ H){
  __shared__ int h[NN];
  int b = blockIdx.x;            // 0..351
  int r = b >> 4, c = b & 15;
  int t = threadIdx.x;
  #pragma unroll
  for (int u=0; u<NN/256; u++) h[t + 256*u] = 0;
  __syncthreads();
  const int* dstp = ei + (r*2+1)*EE + c*EPC;
  for (int e = t; e < EPC; e += 256) atomicAdd(&h[dstp[e]], 1);
  __syncthreads();
  int* Hp = H + (r*CH + c)*NN;
  #pragma unroll
  for (int u=0; u<NN/256; u++) Hp[t + 256*u] = h[t + 256*u];
}

// per-relation: row offsets, degrees, and per-(chunk,dst) cursor bases
__global__ void __launch_bounds__(256) scan2_k(const int* __restrict__ H,
                                               int* __restrict__ Hbase,
                                               int* __restrict__ offs,
                                               int* __restrict__ cnt){
  __shared__ int part[256];
  int r = blockIdx.x, t = threadIdx.x;   // 22 blocks x 256 threads
  int tot[8]; int s = 0;
  #pragma unroll
  for (int u=0; u<8; u++){
    int d = t*8 + u;
    int sum = 0;
    #pragma unroll
    for (int c=0; c<CH; c++) sum += H[(r*CH + c)*NN + d];
    tot[u] = sum; s += sum;
  }
  part[t] = s;
  __syncthreads();
  for (int off=1; off<256; off<<=1){
    int v = (t>=off) ? part[t-off] : 0;
    __syncthreads();
    part[t] += v;
    __syncthreads();
  }
  int run = r*EE + part[t] - s;
  #pragma unroll
  for (int u=0; u<8; u++){
    int d = t*8 + u;
    offs[r*NN + d] = run;
    cnt [r*NN + d] = tot[u];
    int base = run;
    #pragma unroll
    for (int c=0; c<CH; c++){
      Hbase[(r*CH + c)*NN + d] = base;
      base += H[(r*CH + c)*NN + d];
    }
    run += tot[u];
  }
}

// chunk-local scatter: LDS cursor ranks within chunk; ranges disjoint by build
__global__ void __launch_bounds__(256) scat2_k(const int* __restrict__ ei,
                                               const int* __restrict__ Hbase,
                                               int* __restrict__ csr){
  __shared__ int cur[NN];
  int b = blockIdx.x;
  int r = b >> 4, c = b & 15;
  int t = threadIdx.x;
  const int* Hp = Hbase + (r*CH + c)*NN;
  #pragma unroll
  for (int u=0; u<NN/256; u++) cur[t + 256*u] = Hp[t + 256*u];
  __syncthreads();
  const int* srcp = ei + (r*2+0)*EE + c*EPC;
  const int* dstp = ei + (r*2+1)*EE + c*EPC;
  for (int e = t; e < EPC; e += 256){
    int pos = atomicAdd(&cur[dstp[e]], 1);
    csr[pos] = srcp[e];
  }
}

// ---- prep: weights for BOTH layers + x0->bf16 cast, one launch ------------
__global__ void prep_k(const float* __restrict__ Wl, const float* __restrict__ Wr,
                       const float* __restrict__ bl, const float* __restrict__ x0,
                       u16* __restrict__ Bt2, float* __restrict__ bias2,
                       u16* __restrict__ xb){
  int b = blockIdx.x;
  if (b < (2*23*65536)/256){
    int idx = b*256 + threadIdx.x;
    int l  = idx / (23*65536);
    int r2 = idx - l*(23*65536);
    int plane = r2 >> 16, rem = r2 & 65535;
    if (plane < RR){
      Bt2[idx] = f2bf(Wl[((size_t)l*RR + plane)*65536 + rem]);
    } else {
      float s = 0.f;
      for (int r=0;r<RR;r++) s += Wr[((size_t)l*RR + r)*65536 + rem];
      Bt2[idx] = f2bf(s);
    }
    if (plane == 0 && rem < HH){
      float bsum = 0.f;
      for (int r=0;r<RR;r++) bsum += bl[((size_t)l*RR + r)*HH + rem];
      bias2[l*HH + rem] = bsum;
    }
  } else {
    int idx = (b - (2*23*65536)/256)*256 + threadIdx.x;   // 65536 threads
    const float4* p = (const float4*)x0 + (size_t)idx*2;
    float4 a = p[0], c = p[1];
    u16x8 st;
    st[0]=f2bf(a.x); st[1]=f2bf(a.y); st[2]=f2bf(a.z); st[3]=f2bf(a.w);
    st[4]=f2bf(c.x); st[5]=f2bf(c.y); st[6]=f2bf(c.z); st[7]=f2bf(c.w);
    ((u16x8*)xb)[idx] = st;
  }
}

// ---- gather-mean into global bf16 G[p][n][h] ------------------------------
__global__ void __launch_bounds__(256) gather_k(
    const u16* __restrict__ xb, const int* __restrict__ offs,
    const int* __restrict__ cnt, const int* __restrict__ csr,
    u16* __restrict__ G)
{
  int p    = blockIdx.y;
  int m0   = blockIdx.x * 32;
  int wv   = threadIdx.x >> 6;
  int lane = threadIdx.x & 63;
  int half = lane >> 5;
  int c    = (lane & 31) * 8;

  for (int t = 0; t < 4; t++){
    int n   = m0 + wv*8 + t*2 + half;
    int off = offs[p*NN + n];
    int deg = cnt [p*NN + n];
    int dmax = max(deg, __shfl_xor(deg, 32));
    float a[8];
    #pragma unroll
    for (int u=0;u<8;u++) a[u] = 0.f;
    for (int e = 0; e < dmax; e++){
      if (e < deg){
        int s = csr[off + e];
        u16x8 v = *(const u16x8*)(xb + (size_t)s*HH + c);
        #pragma unroll
        for (int u=0;u<8;u++) a[u] += bf2f(v[u]);
      }
    }
    float inv = 1.0f / fmaxf((float)deg, 1.0f);
    u16x8 st;
    #pragma unroll
    for (int u=0;u<8;u++) st[u] = f2bf(a[u]*inv);
    *(u16x8*)(G + ((size_t)p*NN + n)*HH + c) = st;
  }
}

// ---- fused stacked-K GEMM + split-K LDS reduce + bias + relu + casts ------
__global__ void __launch_bounds__(512) fgr_k(
    const u16* __restrict__ G, const u16* __restrict__ xb,
    const u16* __restrict__ Bt, const float* __restrict__ bias,
    float* __restrict__ x1, u16* __restrict__ xbo)
{
  __shared__ float red[8][32][32];   // 32 KB
  int m0   = blockIdx.x * 32;
  int y    = blockIdx.y;
  int wid  = threadIdx.x >> 6;
  int lane = threadIdx.x & 63;
  int c    = wid & 1;
  int kc   = wid >> 1;
  int col  = y*64 + c*32 + (lane & 31);
  int khalf = (lane >> 5) * 8;
  int arow  = lane & 31;

  f32x16 acc;
  #pragma unroll
  for (int i=0;i<16;i++) acc[i]=0.f;

  int p0 = kc*6, p1 = min(p0+6, 23);
  for (int p = p0; p < p1; p++){
    const u16* Ap = ((p < RR) ? (G + (size_t)p*NN*HH) : xb)
                    + (size_t)(m0 + arow)*HH + khalf;
    const u16* Bp = Bt + (size_t)p*65536 + (size_t)col*HH + khalf;
    #pragma unroll
    for (int kk = 0; kk < HH; kk += 16){
      bf16x8 af = *(const bf16x8*)(Ap + kk);
      bf16x8 bf = *(const bf16x8*)(Bp + kk);
      acc = __builtin_amdgcn_mfma_f32_32x32x16_bf16(af, bf, acc, 0, 0, 0);
    }
  }
  #pragma unroll
  for (int reg=0; reg<16; reg++){
    int row = (reg&3) + 8*(reg>>2) + 4*(lane>>5);
    red[wid][row][lane & 31] = acc[reg];
  }
  __syncthreads();

  int t    = threadIdx.x;
  int cc   = t >> 8;
  int rrow = (t >> 3) & 31;
  int c4   = (t & 7) * 4;
  float4 v = *(const float4*)&red[cc][rrow][c4];
  #pragma unroll
  for (int k=1;k<4;k++){
    float4 w = *(const float4*)&red[k*2+cc][rrow][c4];
    v.x+=w.x; v.y+=w.y; v.z+=w.z; v.w+=w.w;
  }
  int gcol = y*64 + cc*32 + c4;
  float4 b = *(const float4*)(bias + gcol);
  v.x = fmaxf(v.x+b.x, 0.f);
  v.y = fmaxf(v.y+b.y, 0.f);
  v.z = fmaxf(v.z+b.z, 0.f);
  v.w = fmaxf(v.w+b.w, 0.f);
  size_t o = (size_t)(m0 + rrow)*HH + gcol;
  *(float4*)(x1 + o) = v;
  ushort4 st; st.x=f2bf(v.x); st.y=f2bf(v.y); st.z=f2bf(v.z); st.w=f2bf(v.w);
  *(ushort4*)(xbo + o) = st;
}

// ---- coefficients: m[n][r], p[n][r] = m*a ---------------------------------
__global__ void coeff_k(const float* __restrict__ x2, const float* __restrict__ Wa,
                        const float* __restrict__ ba, const float* __restrict__ Wm,
                        const float* __restrict__ bm,
                        float* __restrict__ mbuf, float* __restrict__ pbuf){
  int idx = blockIdx.x*256 + threadIdx.x;   // NN*RR = 45056 exact
  int n = idx / RR, r = idx - n*RR;
  const float4* xr = (const float4*)(x2 + (size_t)n*HH);
  const float4* wa = (const float4*)(Wa + (size_t)r*HH);
  const float4* wm = (const float4*)(Wm + (size_t)r*HH);
  float da=0.f, dm=0.f;
  #pragma unroll 4
  for (int h=0; h<HH/4; h++){
    float4 xv = xr[h], av = wa[h], mv = wm[h];
    da += xv.x*av.x + xv.y*av.y + xv.z*av.z + xv.w*av.w;
    dm += xv.x*mv.x + xv.y*mv.y + xv.z*mv.z + xv.w*mv.w;
  }
  float a = fmaxf(da + ba[r], 0.f);
  float m = fmaxf(dm + bm[r], 0.f);
  mbuf[idx] = m;
  pbuf[idx] = m*a;
}

// ---- final: LDS-staged adj (round-4; at HBM floor) ------------------------
__global__ void __launch_bounds__(256) final_k(
    const float* __restrict__ adj, const float* __restrict__ mbuf,
    const float* __restrict__ pbuf, float* __restrict__ out){
  __shared__ float sadj[256*RR];                 // 22528 B
  int i  = blockIdx.y;
  int jb = blockIdx.x*256;
  int t  = threadIdx.x;
  const float4* base = (const float4*)(adj + ((size_t)i*NN + jb)*RR);
  #pragma unroll
  for (int k = 0; k < 6; k++){
    int idx = k*256 + t;
    if (idx < (256*RR)/4) ((float4*)sadj)[idx] = base[idx];
  }
  float mv[RR];
  float s = 0.f;
  #pragma unroll
  for (int r=0;r<RR;r++){ mv[r] = mbuf[i*RR+r]; s += pbuf[i*RR+r]; }
  __syncthreads();
  float acc = s;
  const float* row = &sadj[t*RR];
  #pragma unroll
  for (int r=0;r<RR;r++) acc += mv[r]*row[r];
  out[(size_t)i*NN + jb + t] = acc;
}

extern "C" void kernel_launch(void* const* d_in, const int* in_sizes, int n_in,
                              void* d_out, int out_size, void* d_ws, size_t ws_size,
                              hipStream_t stream) {
  const float* x0  = (const float*)d_in[0];
  const float* adj = (const float*)d_in[1];
  const float* Wl  = (const float*)d_in[2];
  const float* bl  = (const float*)d_in[3];
  const float* Wr  = (const float*)d_in[4];
  const float* Wa  = (const float*)d_in[5];
  const float* ba  = (const float*)d_in[6];
  const float* Wm  = (const float*)d_in[7];
  const float* bm  = (const float*)d_in[8];
  const int*   ei  = (const int*)d_in[9];
  float* out = (float*)d_out;

  char* w = (char*)d_ws;
  auto alloc = [&](size_t bytes){ char* p = w; w += (bytes + 255) & ~255ull; return p; };
  int*   H      = (int*)  alloc((size_t)RR*CH*NN*4);   // 5.8 MB chunk hists
  int*   Hbase  = (int*)  alloc((size_t)RR*CH*NN*4);   // 5.8 MB chunk cursors
  int*   offs   = (int*)  alloc((size_t)RR*NN*4);
  int*   cnt    = (int*)  alloc((size_t)RR*NN*4);
  int*   csr    = (int*)  alloc((size_t)RR*EE*4);
  u16*   Bt2    = (u16*)  alloc((size_t)2*(RR+1)*HH*HH*2);
  float* bias2  = (float*)alloc((size_t)2*HH*4);
  u16*   G      = (u16*)  alloc((size_t)RR*NN*HH*2);   // 22 MB stacked-K bf16
  u16*   xb0    = (u16*)  alloc((size_t)NN*HH*2);
  u16*   xb1    = (u16*)  alloc((size_t)NN*HH*2);
  float* x1     = (float*)alloc((size_t)NN*HH*4);
  float* mbuf   = (float*)alloc((size_t)NN*RR*4);
  float* pbuf   = (float*)alloc((size_t)NN*RR*4);

  hist_k <<<RR*CH, 256, 0, stream>>>(ei, H);
  scan2_k<<<RR,    256, 0, stream>>>(H, Hbase, offs, cnt);
  scat2_k<<<RR*CH, 256, 0, stream>>>(ei, Hbase, csr);
  prep_k<<<(2*23*65536)/256 + (NN*HH/8)/256, 256, 0, stream>>>(Wl, Wr, bl, x0,
                                                               Bt2, bias2, xb0);
  // layer 0
  gather_k<<<dim3(NN/32, RR), 256, 0, stream>>>(xb0, offs, cnt, csr, G);
  fgr_k   <<<dim3(NN/32, 4), 512, 0, stream>>>(G, xb0, Bt2, bias2, x1, xb1);
  // layer 1
  gather_k<<<dim3(NN/32, RR), 256, 0, stream>>>(xb1, offs, cnt, csr, G);
  fgr_k   <<<dim3(NN/32, 4), 512, 0, stream>>>(G, xb1, Bt2 + (size_t)(RR+1)*HH*HH,
                                               bias2 + HH, x1, xb0);

  coeff_k<<<(NN*RR)/256, 256, 0, stream>>>(x1, Wa, ba, Wm, bm, mbuf, pbuf);
  final_k<<<dim3(NN/256, NN), 256, 0, stream>>>(adj, mbuf, pbuf, out);
}